// Round 1
// baseline (962.805 us; speedup 1.0000x reference)
//
#include <hip/hip_runtime.h>

// GATv2 ×2 + global_add_pool + MLP. fp32 throughout (accuracy budget ~7e-5 rel).
// Sizes fixed per reference.
constexpr int Nn    = 20000;
constexpr int Ee    = 320000;
constexpr int Dd    = 1280;
constexpr int Gg    = 256;
constexpr int ETOT  = Ee + Nn;   // real edges + self loops
#define NEG 0.2f

__device__ inline float lrelu(float v){ return v > 0.f ? v : NEG * v; }
__device__ inline float wave_sum(float v){
  #pragma unroll
  for(int o = 32; o; o >>= 1) v += __shfl_xor(v, o, 64);
  return v;
}
__device__ inline float wave_max(float v){
  #pragma unroll
  for(int o = 32; o; o >>= 1) v = fmaxf(v, __shfl_xor(v, o, 64));
  return v;
}

// ---------------- CSR build (by destination), rebuilt every call ----------------
__global__ void fill_int(int* p, int n, int v){
  int i = blockIdx.x * blockDim.x + threadIdx.x;
  if(i < n) p[i] = v;
}
__global__ void zero_float(float* p, int n){
  int i = blockIdx.x * blockDim.x + threadIdx.x;
  if(i < n) p[i] = 0.f;
}
__global__ void hist_dst(const int* __restrict__ dst, int* __restrict__ deg){
  int e = blockIdx.x * blockDim.x + threadIdx.x;
  if(e < Ee) atomicAdd(&deg[dst[e]], 1);
}
__global__ __launch_bounds__(1024) void scan_deg(const int* __restrict__ deg,
                                                 int* __restrict__ rowptr,
                                                 int* __restrict__ cursor){
  __shared__ int part[1024];
  int t = threadIdx.x;
  const int CH = (Nn + 1023) / 1024;      // 20
  int base = t * CH;
  int s = 0;
  for(int j = 0; j < CH; j++){ int idx = base + j; if(idx < Nn) s += deg[idx]; }
  part[t] = s;
  __syncthreads();
  for(int off = 1; off < 1024; off <<= 1){
    int v = (t >= off) ? part[t - off] : 0;
    __syncthreads();
    part[t] += v;
    __syncthreads();
  }
  int acc = part[t] - s;                  // exclusive prefix of this chunk
  for(int j = 0; j < CH; j++){
    int idx = base + j;
    if(idx < Nn){ rowptr[idx] = acc; cursor[idx] = acc; acc += deg[idx]; }
  }
  if(t == 1023) rowptr[Nn] = part[1023];  // = ETOT
}
__global__ void scatter_edges(const int* __restrict__ dst, int* __restrict__ cursor,
                              int* __restrict__ eid){
  int e = blockIdx.x * blockDim.x + threadIdx.x;
  if(e >= ETOT) return;
  int d = (e < Ee) ? dst[e] : (e - Ee);
  int pos = atomicAdd(&cursor[d], 1);
  eid[pos] = e;
}

// ---------------- fp32 SGEMM: Y = X @ [Wa|Wb] + [ba|bb], split outputs ----------------
#define BM 128
#define BN 128
#define BK 16
__global__ __launch_bounds__(256) void gemm_dual(
    const float* __restrict__ X, int M, int K,
    const float* __restrict__ Wa, const float* __restrict__ ba, int Ca,
    const float* __restrict__ Wb, const float* __restrict__ bb, int Cb,
    float* __restrict__ Ya, float* __restrict__ Yb)
{
  __shared__ float As[BK][BM + 4];
  __shared__ float Bs[BK][BN + 4];
  const int bm = blockIdx.x * BM;
  const int bn = blockIdx.y * BN;
  const int tid = threadIdx.x;
  const int tx = tid & 15;
  const int ty = tid >> 4;
  float c[8][8] = {};
  for(int k0 = 0; k0 < K; k0 += BK){
    #pragma unroll
    for(int i = 0; i < 2; i++){           // A tile: 128 rows x 16 k, float4 loads
      int idx = tid + i * 256;
      int r  = idx >> 2;
      int kc = (idx & 3) << 2;
      int gm = bm + r;
      float4 v = make_float4(0.f, 0.f, 0.f, 0.f);
      if(gm < M) v = *(const float4*)(X + (size_t)gm * K + k0 + kc);
      As[kc + 0][r] = v.x; As[kc + 1][r] = v.y; As[kc + 2][r] = v.z; As[kc + 3][r] = v.w;
    }
    #pragma unroll
    for(int i = 0; i < 2; i++){           // B tile: 16 k x 128 cols (col picks Wa/Wb)
      int idx = tid + i * 256;
      int kr = idx >> 5;
      int n  = (idx & 31) << 2;
      int gn = bn + n;
      int gk = k0 + kr;
      float4 v;
      if(gn < Ca) v = *(const float4*)(Wa + (size_t)gk * Ca + gn);
      else        v = *(const float4*)(Wb + (size_t)gk * Cb + (gn - Ca));
      *(float4*)(&Bs[kr][n]) = v;
    }
    __syncthreads();
    #pragma unroll
    for(int k = 0; k < BK; k++){
      // cols per thread: {tx*4..+3} and {64+tx*4..+3} -> 2-way LDS aliasing (free)
      float4 a0 = *(const float4*)&As[k][ty * 8];
      float4 a1 = *(const float4*)&As[k][ty * 8 + 4];
      float4 b0 = *(const float4*)&Bs[k][tx * 4];
      float4 b1 = *(const float4*)&Bs[k][64 + tx * 4];
      float a[8] = {a0.x, a0.y, a0.z, a0.w, a1.x, a1.y, a1.z, a1.w};
      float b[8] = {b0.x, b0.y, b0.z, b0.w, b1.x, b1.y, b1.z, b1.w};
      #pragma unroll
      for(int i = 0; i < 8; i++)
        #pragma unroll
        for(int j = 0; j < 8; j++)
          c[i][j] = fmaf(a[i], b[j], c[i][j]);
    }
    __syncthreads();
  }
  #pragma unroll
  for(int i = 0; i < 8; i++){
    int gm = bm + ty * 8 + i;
    if(gm < M){
      #pragma unroll
      for(int j = 0; j < 8; j++){
        int gn = bn + ((j < 4) ? (tx * 4 + j) : (64 + tx * 4 + (j - 4)));
        if(gn < Ca) Ya[(size_t)gm * Ca + gn]        = c[i][j] + ba[gn];
        else        Yb[(size_t)gm * Cb + (gn - Ca)] = c[i][j] + bb[gn - Ca];
      }
    }
  }
}

// ---------------- layer 1 edge logits: wave per edge, 4 heads x 64 ch ----------------
__global__ __launch_bounds__(256) void edge_logits1(
    const int* __restrict__ src, const int* __restrict__ dst,
    const float* __restrict__ XL, const float* __restrict__ XR,
    const float* __restrict__ att, float* __restrict__ logit)
{
  int e = blockIdx.x * 4 + (threadIdx.x >> 6);
  int lane = threadIdx.x & 63;
  if(e >= ETOT) return;
  int s = (e < Ee) ? src[e] : (e - Ee);
  int d = (e < Ee) ? dst[e] : (e - Ee);
  float4 xl = *(const float4*)(XL + (size_t)s * 256 + lane * 4);
  float4 xr = *(const float4*)(XR + (size_t)d * 256 + lane * 4);
  float4 a  = *(const float4*)(att + lane * 4);   // att flat [h*64+c] == channel idx
  float p = lrelu(xl.x + xr.x) * a.x + lrelu(xl.y + xr.y) * a.y
          + lrelu(xl.z + xr.z) * a.z + lrelu(xl.w + xr.w) * a.w;
  #pragma unroll
  for(int o = 8; o; o >>= 1) p += __shfl_xor(p, o, 64);  // reduce 16 lanes/head
  if((lane & 15) == 0) logit[(size_t)e * 4 + (lane >> 4)] = p;
}

// ---------------- layer 1 per-dst softmax + aggregation: wave per node ----------------
__global__ __launch_bounds__(256) void node_agg1(
    const int* __restrict__ rowptr, const int* __restrict__ eid,
    const int* __restrict__ src,
    const float* __restrict__ XL, const float* __restrict__ logit,
    const float* __restrict__ bias, float* __restrict__ H)
{
  int node = blockIdx.x * 4 + (threadIdx.x >> 6);
  int lane = threadIdx.x & 63;
  if(node >= Nn) return;
  int r0 = rowptr[node], r1 = rowptr[node + 1];
  float m0 = -1e30f, m1 = -1e30f, m2 = -1e30f, m3 = -1e30f;
  for(int k = r0 + lane; k < r1; k += 64){
    const float4 lg = *(const float4*)(logit + (size_t)eid[k] * 4);
    m0 = fmaxf(m0, lg.x); m1 = fmaxf(m1, lg.y); m2 = fmaxf(m2, lg.z); m3 = fmaxf(m3, lg.w);
  }
  m0 = wave_max(m0); m1 = wave_max(m1); m2 = wave_max(m2); m3 = wave_max(m3);
  float d0 = 0, d1 = 0, d2 = 0, d3 = 0;
  for(int k = r0 + lane; k < r1; k += 64){
    const float4 lg = *(const float4*)(logit + (size_t)eid[k] * 4);
    d0 += expf(lg.x - m0); d1 += expf(lg.y - m1); d2 += expf(lg.z - m2); d3 += expf(lg.w - m3);
  }
  d0 = wave_sum(d0); d1 = wave_sum(d1); d2 = wave_sum(d2); d3 = wave_sum(d3);
  int h = lane >> 4;
  float mh   = (h == 0) ? m0 : (h == 1) ? m1 : (h == 2) ? m2 : m3;
  float dh   = (h == 0) ? d0 : (h == 1) ? d1 : (h == 2) ? d2 : d3;
  float invh = 1.f / (dh + 1e-16f);
  float4 acc = make_float4(0.f, 0.f, 0.f, 0.f);
  for(int k = r0; k < r1; k++){
    int e = eid[k];
    int s = (e < Ee) ? src[e] : node;
    float alpha = expf(logit[(size_t)e * 4 + h] - mh) * invh;
    const float4 xl = *(const float4*)(XL + (size_t)s * 256 + lane * 4);
    acc.x = fmaf(alpha, xl.x, acc.x); acc.y = fmaf(alpha, xl.y, acc.y);
    acc.z = fmaf(alpha, xl.z, acc.z); acc.w = fmaf(alpha, xl.w, acc.w);
  }
  const float4 b = *(const float4*)(bias + lane * 4);
  float4 o;
  o.x = fmaxf(acc.x + b.x, 0.f); o.y = fmaxf(acc.y + b.y, 0.f);
  o.z = fmaxf(acc.z + b.z, 0.f); o.w = fmaxf(acc.w + b.w, 0.f);
  *(float4*)(H + (size_t)node * 256 + lane * 4) = o;
}

// ---------------- layer 2 (heads=1, C=64) ----------------
__global__ __launch_bounds__(256) void edge_logits2(
    const int* __restrict__ src, const int* __restrict__ dst,
    const float* __restrict__ XL, const float* __restrict__ XR,
    const float* __restrict__ att, float* __restrict__ logit)
{
  int e = blockIdx.x * 4 + (threadIdx.x >> 6);
  int lane = threadIdx.x & 63;
  if(e >= ETOT) return;
  int s = (e < Ee) ? src[e] : (e - Ee);
  int d = (e < Ee) ? dst[e] : (e - Ee);
  float v = lrelu(XL[(size_t)s * 64 + lane] + XR[(size_t)d * 64 + lane]) * att[lane];
  v = wave_sum(v);
  if(lane == 0) logit[e] = v;
}
__global__ __launch_bounds__(256) void node_agg2(
    const int* __restrict__ rowptr, const int* __restrict__ eid,
    const int* __restrict__ src,
    const float* __restrict__ XL, const float* __restrict__ logit,
    const float* __restrict__ bias, float* __restrict__ H)
{
  int node = blockIdx.x * 4 + (threadIdx.x >> 6);
  int lane = threadIdx.x & 63;
  if(node >= Nn) return;
  int r0 = rowptr[node], r1 = rowptr[node + 1];
  float mx = -1e30f;
  for(int k = r0 + lane; k < r1; k += 64) mx = fmaxf(mx, logit[eid[k]]);
  mx = wave_max(mx);
  float dn = 0.f;
  for(int k = r0 + lane; k < r1; k += 64) dn += expf(logit[eid[k]] - mx);
  dn = wave_sum(dn);
  float inv = 1.f / (dn + 1e-16f);
  float acc = 0.f;
  for(int k = r0; k < r1; k++){
    int e = eid[k];
    int s = (e < Ee) ? src[e] : node;
    float alpha = expf(logit[e] - mx) * inv;
    acc = fmaf(alpha, XL[(size_t)s * 64 + lane], acc);
  }
  H[(size_t)node * 64 + lane] = fmaxf(acc + bias[lane], 0.f);
}

// ---------------- pool + MLP head ----------------
__global__ void pool_kernel(const float* __restrict__ H2, const int* __restrict__ batch,
                            float* __restrict__ GP){
  int gid = blockIdx.x * blockDim.x + threadIdx.x;
  if(gid >= Nn * 16) return;
  int i = gid >> 4;
  int c = (gid & 15) * 4;
  int b = batch[i];
  const float4 v = *(const float4*)(H2 + (size_t)i * 64 + c);
  atomicAdd(&GP[b * 64 + c + 0], v.x);
  atomicAdd(&GP[b * 64 + c + 1], v.y);
  atomicAdd(&GP[b * 64 + c + 2], v.z);
  atomicAdd(&GP[b * 64 + c + 3], v.w);
}
__global__ __launch_bounds__(64) void mlp_head(const float* __restrict__ GP,
                                               const float* __restrict__ W3,
                                               const float* __restrict__ b3,
                                               const float* __restrict__ W4,
                                               const float* __restrict__ b4,
                                               float* __restrict__ out){
  int g = blockIdx.x;
  int j = threadIdx.x;
  __shared__ float sh[64];
  sh[j] = GP[(size_t)g * 64 + j];
  __syncthreads();
  float t = b3[j];
  #pragma unroll
  for(int k = 0; k < 64; k++) t = fmaf(sh[k], W3[k * 64 + j], t);
  t = fmaxf(t, 0.f);
  float p = t * W4[j];
  p = wave_sum(p);
  if(j == 0) out[g] = p + b4[0];
}

extern "C" void kernel_launch(void* const* d_in, const int* in_sizes, int n_in,
                              void* d_out, int out_size, void* d_ws, size_t ws_size,
                              hipStream_t stream)
{
  const float* x     = (const float*)d_in[0];
  const int*   ei    = (const int*)d_in[1];
  const int*   batch = (const int*)d_in[2];
  const float* Wl1   = (const float*)d_in[3];
  const float* bl1   = (const float*)d_in[4];
  const float* Wr1   = (const float*)d_in[5];
  const float* br1   = (const float*)d_in[6];
  const float* att1  = (const float*)d_in[7];
  const float* bias1 = (const float*)d_in[8];
  const float* Wl2   = (const float*)d_in[9];
  const float* bl2   = (const float*)d_in[10];
  const float* Wr2   = (const float*)d_in[11];
  const float* br2   = (const float*)d_in[12];
  const float* att2  = (const float*)d_in[13];
  const float* bias2 = (const float*)d_in[14];
  const float* W3    = (const float*)d_in[15];
  const float* b3    = (const float*)d_in[16];
  const float* W4    = (const float*)d_in[17];
  const float* b4    = (const float*)d_in[18];
  float* out = (float*)d_out;

  char* ws = (char*)d_ws;
  size_t off = 0;
  auto alloc = [&](size_t bytes) -> void* {
    void* p = ws + off;
    off += (bytes + 255) & ~(size_t)255;
    return p;
  };
  float* XL1  = (float*)alloc((size_t)Nn * 256 * 4);   // 20.48 MB (reused as XL2)
  float* XR1  = (float*)alloc((size_t)Nn * 256 * 4);   // 20.48 MB (reused as XR2)
  float* H1   = (float*)alloc((size_t)Nn * 256 * 4);   // 20.48 MB
  float* LOG1 = (float*)alloc((size_t)ETOT * 4 * 4);   // 5.44 MB (reused as LOG2)
  int*   rowptr = (int*)alloc((size_t)(Nn + 1) * 4);
  int*   deg    = (int*)alloc((size_t)Nn * 4);
  int*   cursor = (int*)alloc((size_t)Nn * 4);
  int*   eid    = (int*)alloc((size_t)ETOT * 4);
  float* H2   = (float*)alloc((size_t)Nn * 64 * 4);    // 5.12 MB
  float* GP   = (float*)alloc((size_t)Gg * 64 * 4);
  float* XL2 = XL1;
  float* XR2 = XR1;
  float* LOG2 = LOG1;

  const int* srcA = ei;        // edge_index[0]
  const int* dstA = ei + Ee;   // edge_index[1]

  // CSR by destination (self-loop per node folded in via deg init = 1)
  fill_int<<<(Nn + 255) / 256, 256, 0, stream>>>(deg, Nn, 1);
  hist_dst<<<(Ee + 255) / 256, 256, 0, stream>>>(dstA, deg);
  scan_deg<<<1, 1024, 0, stream>>>(deg, rowptr, cursor);
  scatter_edges<<<(ETOT + 255) / 256, 256, 0, stream>>>(dstA, cursor, eid);

  // layer 1
  dim3 g1((Nn + BM - 1) / BM, 512 / BN);
  gemm_dual<<<g1, 256, 0, stream>>>(x, Nn, Dd, Wl1, bl1, 256, Wr1, br1, 256, XL1, XR1);
  edge_logits1<<<(ETOT + 3) / 4, 256, 0, stream>>>(srcA, dstA, XL1, XR1, att1, LOG1);
  node_agg1<<<(Nn + 3) / 4, 256, 0, stream>>>(rowptr, eid, srcA, XL1, LOG1, bias1, H1);

  // layer 2
  dim3 g2((Nn + BM - 1) / BM, 1);
  gemm_dual<<<g2, 256, 0, stream>>>(H1, Nn, 256, Wl2, bl2, 64, Wr2, br2, 64, XL2, XR2);
  edge_logits2<<<(ETOT + 3) / 4, 256, 0, stream>>>(srcA, dstA, XL2, XR2, att2, LOG2);
  node_agg2<<<(Nn + 3) / 4, 256, 0, stream>>>(rowptr, eid, srcA, XL2, LOG2, bias2, H2);

  // pool + head
  zero_float<<<(Gg * 64 + 255) / 256, 256, 0, stream>>>(GP, Gg * 64);
  pool_kernel<<<(Nn * 16 + 255) / 256, 256, 0, stream>>>(H2, batch, GP);
  mlp_head<<<Gg, 64, 0, stream>>>(GP, W3, b3, W4, b4, out);
}

// Round 2
// 611.713 us; speedup vs baseline: 1.5739x; 1.5739x over previous
//
#include <hip/hip_runtime.h>

constexpr int Nn    = 20000;
constexpr int Ee    = 320000;
constexpr int Dd    = 1280;
constexpr int Gg    = 256;
constexpr int ETOT  = Ee + Nn;
#define NEG 0.2f

typedef __attribute__((ext_vector_type(8))) short s8v;     // 8 bf16 = 4 VGPR
typedef __attribute__((ext_vector_type(4))) float f4v;     // MFMA acc

__device__ inline float lrelu(float v){ return v > 0.f ? v : NEG * v; }
__device__ inline float wave_sum(float v){
  #pragma unroll
  for(int o = 32; o; o >>= 1) v += __shfl_xor(v, o, 64);
  return v;
}
__device__ inline unsigned short f2bf(float x){
  unsigned u = __float_as_uint(x);
  return (unsigned short)((u + 0x7FFFu + ((u >> 16) & 1u)) >> 16);   // RNE
}
__device__ inline float bf2f(unsigned short h){ return __uint_as_float(((unsigned)h) << 16); }

__device__ inline void async_cp16(const void* g, void* l){
  __builtin_amdgcn_global_load_lds((const __attribute__((address_space(1))) void*)g,
                                   (__attribute__((address_space(3))) void*)l, 16, 0, 0);
}

// ---------------- CSR build (by destination) ----------------
__global__ void fill_int(int* p, int n, int v){
  int i = blockIdx.x * blockDim.x + threadIdx.x;
  if(i < n) p[i] = v;
}
__global__ void zero_float(float* p, int n){
  int i = blockIdx.x * blockDim.x + threadIdx.x;
  if(i < n) p[i] = 0.f;
}
__global__ void hist_dst(const int* __restrict__ dst, int* __restrict__ deg){
  int e = blockIdx.x * blockDim.x + threadIdx.x;
  if(e < Ee) atomicAdd(&deg[dst[e]], 1);
}
__global__ __launch_bounds__(1024) void scan_deg(const int* __restrict__ deg,
                                                 int* __restrict__ rowptr,
                                                 int* __restrict__ cursor){
  __shared__ int part[1024];
  int t = threadIdx.x;
  const int CH = (Nn + 1023) / 1024;
  int base = t * CH;
  int s = 0;
  for(int j = 0; j < CH; j++){ int idx = base + j; if(idx < Nn) s += deg[idx]; }
  part[t] = s;
  __syncthreads();
  for(int off = 1; off < 1024; off <<= 1){
    int v = (t >= off) ? part[t - off] : 0;
    __syncthreads();
    part[t] += v;
    __syncthreads();
  }
  int acc = part[t] - s;
  for(int j = 0; j < CH; j++){
    int idx = base + j;
    if(idx < Nn){ rowptr[idx] = acc; cursor[idx] = acc; acc += deg[idx]; }
  }
  if(t == 1023) rowptr[Nn] = part[1023];
}
__global__ void scatter_edges(const int* __restrict__ dst, int* __restrict__ cursor,
                              int* __restrict__ eid){
  int e = blockIdx.x * blockDim.x + threadIdx.x;
  if(e >= ETOT) return;
  int d = (e < Ee) ? dst[e] : (e - Ee);
  int pos = atomicAdd(&cursor[d], 1);
  eid[pos] = e;
}

// ---------------- W^T split: [512][1280] bf16 hi/lo from Wl|Wr [1280][256] ----------------
__global__ __launch_bounds__(256) void wsplit(const float* __restrict__ Wl,
                                              const float* __restrict__ Wr,
                                              unsigned short* __restrict__ WTH,
                                              unsigned short* __restrict__ WTL){
  __shared__ float t[32][33];
  int k0 = blockIdx.x * 32, n0 = blockIdx.y * 32;
  int tx = threadIdx.x & 31, ty = threadIdx.x >> 5;
  #pragma unroll
  for(int j = 0; j < 4; j++){
    int kk = ty + j * 8;
    int n = n0 + tx;
    t[kk][tx] = (n < 256) ? Wl[(size_t)(k0 + kk) * 256 + n]
                          : Wr[(size_t)(k0 + kk) * 256 + (n - 256)];
  }
  __syncthreads();
  #pragma unroll
  for(int j = 0; j < 4; j++){
    int nn = ty + j * 8;
    float v = t[tx][nn];
    unsigned short hi = f2bf(v);
    unsigned short lo = f2bf(v - bf2f(hi));
    WTH[(size_t)(n0 + nn) * 1280 + k0 + tx] = hi;
    WTL[(size_t)(n0 + nn) * 1280 + k0 + tx] = lo;
  }
}

// ---------------- layer-1 GEMM: split-bf16 MFMA, Y[20000x512] = X @ Wt^T ----------------
// 128x128 tile, BK=32, 4 waves in 2x2, each wave 64x64 via 4x4 16x16x32 MFMA tiles.
// A (X fp32) staged with in-register hi/lo split -> ds_write; B (pre-split bf16) via global_load_lds.
__global__ __launch_bounds__(256) void gemm1_mfma(
    const float* __restrict__ X,
    const unsigned short* __restrict__ WTH, const unsigned short* __restrict__ WTL,
    const float* __restrict__ bl, const float* __restrict__ br,
    float* __restrict__ XL, float* __restrict__ XR)
{
  __shared__ unsigned short sAhi[128 * 32];
  __shared__ unsigned short sAlo[128 * 32];
  __shared__ unsigned short sBhi[128 * 32];
  __shared__ unsigned short sBlo[128 * 32];

  const int tid = threadIdx.x;
  const int lane = tid & 63;
  const int w = tid >> 6;
  const int wm = w & 1, wn = w >> 1;
  const int bm = blockIdx.x * 128;
  const int bn = blockIdx.y * 128;

  f4v acc[4][4] = {};

  // A staging map: idx = r*256+tid in [0,1024): row=idx>>3, seg=idx&7 (4 fp32)
  // B staging map: idx = r*256+tid in [0,512): nrow=idx>>2, kseg=(idx&3)*8 bf16
  for(int k0 = 0; k0 < Dd; k0 += 32){
    float4 av[4];
    #pragma unroll
    for(int r = 0; r < 4; r++){
      int idx = r * 256 + tid;
      int row = idx >> 3, seg = idx & 7;
      int gm = bm + row; if(gm > Nn - 1) gm = Nn - 1;
      av[r] = *(const float4*)(X + (size_t)gm * Dd + k0 + seg * 4);
    }
    __syncthreads();               // previous iteration's LDS reads complete
    #pragma unroll
    for(int r = 0; r < 4; r++){
      int idx = r * 256 + tid;
      int row = idx >> 3, seg = idx & 7;
      int off = row * 32 + seg * 4;
      ushort4 hi, lo;
      float f[4] = {av[r].x, av[r].y, av[r].z, av[r].w};
      unsigned short h[4], l[4];
      #pragma unroll
      for(int q = 0; q < 4; q++){ h[q] = f2bf(f[q]); l[q] = f2bf(f[q] - bf2f(h[q])); }
      hi = make_ushort4(h[0], h[1], h[2], h[3]);
      lo = make_ushort4(l[0], l[1], l[2], l[3]);
      *(ushort4*)&sAhi[off] = hi;
      *(ushort4*)&sAlo[off] = lo;
    }
    #pragma unroll
    for(int r = 0; r < 2; r++){
      int idx = r * 256 + tid;
      int nrow = idx >> 2, kseg = (idx & 3) * 8;
      const unsigned short* gh = WTH + (size_t)(bn + nrow) * Dd + k0 + kseg;
      const unsigned short* gl = WTL + (size_t)(bn + nrow) * Dd + k0 + kseg;
      int ldsbase = (r * 256 + w * 64) * 8;    // wave-uniform, elements
      async_cp16(gh, &sBhi[ldsbase]);
      async_cp16(gl, &sBlo[ldsbase]);
    }
    __syncthreads();               // drains ds_write + global_load_lds

    const int mr = lane & 15;
    const int kq = (lane >> 4) * 8;
    s8v ah[4], al[4];
    #pragma unroll
    for(int i = 0; i < 4; i++){
      int off = (wm * 64 + i * 16 + mr) * 32 + kq;
      ah[i] = *(const s8v*)&sAhi[off];
      al[i] = *(const s8v*)&sAlo[off];
    }
    #pragma unroll
    for(int j = 0; j < 4; j++){
      int off = (wn * 64 + j * 16 + mr) * 32 + kq;
      s8v bh = *(const s8v*)&sBhi[off];
      s8v bl2 = *(const s8v*)&sBlo[off];
      #pragma unroll
      for(int i = 0; i < 4; i++){
        acc[i][j] = __builtin_amdgcn_mfma_f32_16x16x32_bf16(ah[i], bh,  acc[i][j], 0, 0, 0);
        acc[i][j] = __builtin_amdgcn_mfma_f32_16x16x32_bf16(ah[i], bl2, acc[i][j], 0, 0, 0);
        acc[i][j] = __builtin_amdgcn_mfma_f32_16x16x32_bf16(al[i], bh,  acc[i][j], 0, 0, 0);
      }
    }
  }

  // epilogue: C/D map col=lane&15, row=(lane>>4)*4+reg  [m89-verified]
  const float* bias = (bn < 256) ? bl : br;
  float*       Y    = (bn < 256) ? XL : XR;
  const int cb = bn & 255;
  const int quad = lane >> 4, col = lane & 15;
  #pragma unroll
  for(int j = 0; j < 4; j++){
    int gn = cb + wn * 64 + j * 16 + col;
    float bv = bias[gn];
    #pragma unroll
    for(int i = 0; i < 4; i++){
      #pragma unroll
      for(int rg = 0; rg < 4; rg++){
        int gm = bm + wm * 64 + i * 16 + quad * 4 + rg;
        if(gm < Nn) Y[(size_t)gm * 256 + gn] = acc[i][j][rg] + bv;
      }
    }
  }
}

// ---------------- fp32 SGEMM (layer 2): Y = X @ [Wa|Wb] + [ba|bb] ----------------
#define BM 128
#define BN 128
#define BK 16
__global__ __launch_bounds__(256) void gemm_dual(
    const float* __restrict__ X, int M, int K,
    const float* __restrict__ Wa, const float* __restrict__ ba, int Ca,
    const float* __restrict__ Wb, const float* __restrict__ bb, int Cb,
    float* __restrict__ Ya, float* __restrict__ Yb)
{
  __shared__ float As[BK][BM + 4];
  __shared__ float Bs[BK][BN + 4];
  const int bm = blockIdx.x * BM;
  const int bn = blockIdx.y * BN;
  const int tid = threadIdx.x;
  const int tx = tid & 15;
  const int ty = tid >> 4;
  float c[8][8] = {};
  for(int k0 = 0; k0 < K; k0 += BK){
    #pragma unroll
    for(int i = 0; i < 2; i++){
      int idx = tid + i * 256;
      int r  = idx >> 2;
      int kc = (idx & 3) << 2;
      int gm = bm + r;
      float4 v = make_float4(0.f, 0.f, 0.f, 0.f);
      if(gm < M) v = *(const float4*)(X + (size_t)gm * K + k0 + kc);
      As[kc + 0][r] = v.x; As[kc + 1][r] = v.y; As[kc + 2][r] = v.z; As[kc + 3][r] = v.w;
    }
    #pragma unroll
    for(int i = 0; i < 2; i++){
      int idx = tid + i * 256;
      int kr = idx >> 5;
      int n  = (idx & 31) << 2;
      int gn = bn + n;
      int gk = k0 + kr;
      float4 v;
      if(gn < Ca) v = *(const float4*)(Wa + (size_t)gk * Ca + gn);
      else        v = *(const float4*)(Wb + (size_t)gk * Cb + (gn - Ca));
      *(float4*)(&Bs[kr][n]) = v;
    }
    __syncthreads();
    #pragma unroll
    for(int k = 0; k < BK; k++){
      float4 a0 = *(const float4*)&As[k][ty * 8];
      float4 a1 = *(const float4*)&As[k][ty * 8 + 4];
      float4 b0 = *(const float4*)&Bs[k][tx * 4];
      float4 b1 = *(const float4*)&Bs[k][64 + tx * 4];
      float a[8] = {a0.x, a0.y, a0.z, a0.w, a1.x, a1.y, a1.z, a1.w};
      float b[8] = {b0.x, b0.y, b0.z, b0.w, b1.x, b1.y, b1.z, b1.w};
      #pragma unroll
      for(int i = 0; i < 8; i++)
        #pragma unroll
        for(int j = 0; j < 8; j++)
          c[i][j] = fmaf(a[i], b[j], c[i][j]);
    }
    __syncthreads();
  }
  #pragma unroll
  for(int i = 0; i < 8; i++){
    int gm = bm + ty * 8 + i;
    if(gm < M){
      #pragma unroll
      for(int j = 0; j < 8; j++){
        int gn = bn + ((j < 4) ? (tx * 4 + j) : (64 + tx * 4 + (j - 4)));
        if(gn < Ca) Ya[(size_t)gm * Ca + gn]        = c[i][j] + ba[gn];
        else        Yb[(size_t)gm * Cb + (gn - Ca)] = c[i][j] + bb[gn - Ca];
      }
    }
  }
}

// ---------------- fused GATv2 layer 1: wave/node, online softmax, 4 heads x 64 ch ----------------
__global__ __launch_bounds__(256) void gat_fused1(
    const int* __restrict__ rowptr, const int* __restrict__ eid,
    const int* __restrict__ src,
    const float* __restrict__ XL, const float* __restrict__ XR,
    const float* __restrict__ att, const float* __restrict__ bias,
    float* __restrict__ H)
{
  int node = blockIdx.x * 4 + (threadIdx.x >> 6);
  int lane = threadIdx.x & 63;
  if(node >= Nn) return;
  const float4 xr = *(const float4*)(XR + (size_t)node * 256 + lane * 4);
  const float4 a  = *(const float4*)(att + lane * 4);
  int r0 = rowptr[node], r1 = rowptr[node + 1];
  float m = -1e30f, l = 0.f;
  float4 acc = make_float4(0.f, 0.f, 0.f, 0.f);
  for(int k = r0; k < r1; k++){
    int e = eid[k];
    int s = (e < Ee) ? src[e] : node;
    const float4 xl = *(const float4*)(XL + (size_t)s * 256 + lane * 4);
    float p = lrelu(xl.x + xr.x) * a.x + lrelu(xl.y + xr.y) * a.y
            + lrelu(xl.z + xr.z) * a.z + lrelu(xl.w + xr.w) * a.w;
    #pragma unroll
    for(int o = 8; o; o >>= 1) p += __shfl_xor(p, o, 64);   // sum 16 lanes of this head
    float mn = fmaxf(m, p);
    float sc = __expf(m - mn);
    float wg = __expf(p - mn);
    l = l * sc + wg;
    acc.x = acc.x * sc + wg * xl.x;
    acc.y = acc.y * sc + wg * xl.y;
    acc.z = acc.z * sc + wg * xl.z;
    acc.w = acc.w * sc + wg * xl.w;
    m = mn;
  }
  float inv = 1.f / (l + 1e-16f);
  const float4 b = *(const float4*)(bias + lane * 4);
  float4 o;
  o.x = fmaxf(acc.x * inv + b.x, 0.f);
  o.y = fmaxf(acc.y * inv + b.y, 0.f);
  o.z = fmaxf(acc.z * inv + b.z, 0.f);
  o.w = fmaxf(acc.w * inv + b.w, 0.f);
  *(float4*)(H + (size_t)node * 256 + lane * 4) = o;
}

// ---------------- fused GATv2 layer 2: wave/node, heads=1, 64 ch ----------------
__global__ __launch_bounds__(256) void gat_fused2(
    const int* __restrict__ rowptr, const int* __restrict__ eid,
    const int* __restrict__ src,
    const float* __restrict__ XL, const float* __restrict__ XR,
    const float* __restrict__ att, const float* __restrict__ bias,
    float* __restrict__ H)
{
  int node = blockIdx.x * 4 + (threadIdx.x >> 6);
  int lane = threadIdx.x & 63;
  if(node >= Nn) return;
  const float xr = XR[(size_t)node * 64 + lane];
  const float a = att[lane];
  int r0 = rowptr[node], r1 = rowptr[node + 1];
  float m = -1e30f, l = 0.f, acc = 0.f;
  for(int k = r0; k < r1; k++){
    int e = eid[k];
    int s = (e < Ee) ? src[e] : node;
    float xl = XL[(size_t)s * 64 + lane];
    float p = lrelu(xl + xr) * a;
    p = wave_sum(p);
    float mn = fmaxf(m, p);
    float sc = __expf(m - mn);
    float wg = __expf(p - mn);
    l = l * sc + wg;
    acc = acc * sc + wg * xl;
    m = mn;
  }
  float inv = 1.f / (l + 1e-16f);
  H[(size_t)node * 64 + lane] = fmaxf(acc * inv + bias[lane], 0.f);
}

// ---------------- pool + MLP head ----------------
__global__ void pool_kernel(const float* __restrict__ H2, const int* __restrict__ batch,
                            float* __restrict__ GP){
  int gid = blockIdx.x * blockDim.x + threadIdx.x;
  if(gid >= Nn * 16) return;
  int i = gid >> 4;
  int c = (gid & 15) * 4;
  int b = batch[i];
  const float4 v = *(const float4*)(H2 + (size_t)i * 64 + c);
  atomicAdd(&GP[b * 64 + c + 0], v.x);
  atomicAdd(&GP[b * 64 + c + 1], v.y);
  atomicAdd(&GP[b * 64 + c + 2], v.z);
  atomicAdd(&GP[b * 64 + c + 3], v.w);
}
__global__ __launch_bounds__(64) void mlp_head(const float* __restrict__ GP,
                                               const float* __restrict__ W3,
                                               const float* __restrict__ b3,
                                               const float* __restrict__ W4,
                                               const float* __restrict__ b4,
                                               float* __restrict__ out){
  int g = blockIdx.x;
  int j = threadIdx.x;
  __shared__ float sh[64];
  sh[j] = GP[(size_t)g * 64 + j];
  __syncthreads();
  float t = b3[j];
  #pragma unroll
  for(int k = 0; k < 64; k++) t = fmaf(sh[k], W3[k * 64 + j], t);
  t = fmaxf(t, 0.f);
  float p = t * W4[j];
  p = wave_sum(p);
  if(j == 0) out[g] = p + b4[0];
}

extern "C" void kernel_launch(void* const* d_in, const int* in_sizes, int n_in,
                              void* d_out, int out_size, void* d_ws, size_t ws_size,
                              hipStream_t stream)
{
  const float* x     = (const float*)d_in[0];
  const int*   ei    = (const int*)d_in[1];
  const int*   batch = (const int*)d_in[2];
  const float* Wl1   = (const float*)d_in[3];
  const float* bl1   = (const float*)d_in[4];
  const float* Wr1   = (const float*)d_in[5];
  const float* br1   = (const float*)d_in[6];
  const float* att1  = (const float*)d_in[7];
  const float* bias1 = (const float*)d_in[8];
  const float* Wl2   = (const float*)d_in[9];
  const float* bl2   = (const float*)d_in[10];
  const float* Wr2   = (const float*)d_in[11];
  const float* br2   = (const float*)d_in[12];
  const float* att2  = (const float*)d_in[13];
  const float* bias2 = (const float*)d_in[14];
  const float* W3    = (const float*)d_in[15];
  const float* b3    = (const float*)d_in[16];
  const float* W4    = (const float*)d_in[17];
  const float* b4    = (const float*)d_in[18];
  float* out = (float*)d_out;

  char* ws = (char*)d_ws;
  size_t off = 0;
  auto alloc = [&](size_t bytes) -> void* {
    void* p = ws + off;
    off += (bytes + 255) & ~(size_t)255;
    return p;
  };
  float* XL1  = (float*)alloc((size_t)Nn * 256 * 4);   // 20.48 MB (reused as XL2)
  float* XR1  = (float*)alloc((size_t)Nn * 256 * 4);   // 20.48 MB (reused as XR2)
  float* H1   = (float*)alloc((size_t)Nn * 256 * 4);   // 20.48 MB
  unsigned short* WTH = (unsigned short*)alloc((size_t)512 * Dd * 2);  // 1.31 MB
  unsigned short* WTL = (unsigned short*)alloc((size_t)512 * Dd * 2);  // 1.31 MB
  int*   rowptr = (int*)alloc((size_t)(Nn + 1) * 4);
  int*   deg    = (int*)alloc((size_t)Nn * 4);
  int*   cursor = (int*)alloc((size_t)Nn * 4);
  int*   eid    = (int*)alloc((size_t)ETOT * 4);
  float* H2   = (float*)alloc((size_t)Nn * 64 * 4);    // 5.12 MB
  float* GP   = (float*)alloc((size_t)Gg * 64 * 4);
  float* XL2 = XL1;    // layer-1 buffers dead by then
  float* XR2 = XR1;

  const int* srcA = ei;
  const int* dstA = ei + Ee;

  // CSR by destination (self-loop folded in via deg init = 1)
  fill_int<<<(Nn + 255) / 256, 256, 0, stream>>>(deg, Nn, 1);
  hist_dst<<<(Ee + 255) / 256, 256, 0, stream>>>(dstA, deg);
  scan_deg<<<1, 1024, 0, stream>>>(deg, rowptr, cursor);
  scatter_edges<<<(ETOT + 255) / 256, 256, 0, stream>>>(dstA, cursor, eid);

  // layer-1 weight transpose + bf16 hi/lo split
  dim3 gw(Dd / 32, 512 / 32);
  wsplit<<<gw, 256, 0, stream>>>(Wl1, Wr1, WTH, WTL);

  // layer 1
  dim3 g1((Nn + 127) / 128, 4);
  gemm1_mfma<<<g1, 256, 0, stream>>>(x, WTH, WTL, bl1, br1, XL1, XR1);
  gat_fused1<<<(Nn + 3) / 4, 256, 0, stream>>>(rowptr, eid, srcA, XL1, XR1, att1, bias1, H1);

  // layer 2 (fp32, small)
  dim3 g2((Nn + BM - 1) / BM, 1);
  gemm_dual<<<g2, 256, 0, stream>>>(H1, Nn, 256, Wl2, bl2, 64, Wr2, br2, 64, XL2, XR2);
  gat_fused2<<<(Nn + 3) / 4, 256, 0, stream>>>(rowptr, eid, srcA, XL2, XR2, att2, bias2, H2);

  // pool + head
  zero_float<<<(Gg * 64 + 255) / 256, 256, 0, stream>>>(GP, Gg * 64);
  pool_kernel<<<(Nn * 16 + 255) / 256, 256, 0, stream>>>(H2, batch, GP);
  mlp_head<<<Gg, 64, 0, stream>>>(GP, W3, b3, W4, b4, out);
}